// Round 12
// baseline (498.940 us; speedup 1.0000x reference)
//
#include <hip/hip_runtime.h>
#include <hip/hip_bf16.h>

// GCN v22 — v21 base (proven 272.0 us) + 4x16-feature L2-resident slab gather.
//   r21 insight: FETCH_SIZE is TCC(L2)-fill, not HBM — g (12.8 MB) is L3-
//   resident, so gather's 156 MB/dispatch is L2-miss traffic to LLC at the
//   ~3.5 TB/s wall. Fix requires L2-HIT random reads: slab = 16 feats =
//   3.2 MB < 4 MB/XCD L2 (v13 failed at 6.4; v20 failed on TLP).
//   k_gather: 1 dispatch, 4 pass-segments x 25K blocks (400K waves),
//   wave = node x slab; 8 edges/instr (es=lane>>3, j2=lane&7, ushort2) =
//   256 B/instr (v14's proven rate); per-edge VALU identical to v14 across
//   passes; 8-edge chunks -> ~15% clamp waste. rows4 + a-writes NT so the
//   slab owns L2. g/a layout [4][n][16]; k_linc/k_mat remapped (K-split
//   falls on slab boundaries; all v8s accesses stay 16B-aligned).
//   Build kernels byte-identical to v21.

#define FDIM 64
#define NPART 4
#define GPB 64
#define NB 256
#define BW 512
#define MAXP 1024
#define GPLIN 1024

typedef __hip_bfloat16 bf16;
typedef short v8s __attribute__((ext_vector_type(8)));
typedef float v4f __attribute__((ext_vector_type(4)));

static __device__ __forceinline__ float ulo2f(unsigned u) {
    union { unsigned x; float f; } v; v.x = u << 16; return v.f;
}
static __device__ __forceinline__ float uhi2f(unsigned u) {
    union { unsigned x; float f; } v; v.x = u & 0xFFFF0000u; return v.f;
}
static __device__ __forceinline__ unsigned f2bu(float f) {
    bf16 b = __float2bfloat16(f);
    return (unsigned)(*(unsigned short*)&b);
}

// --- dispatch 1: deg u8 partial hist (b < NPART*GPB) ∥ col coarse hist ---
__global__ __launch_bounds__(1024)
void k_h2(const int* __restrict__ row, const int* __restrict__ col,
          unsigned* __restrict__ part, int* __restrict__ M,
          int E, int n, int psize, int psize4, int P, int CH) {
    __shared__ unsigned sm[6256];
    int t = threadIdx.x, b = blockIdx.x;
    if (b < NPART * GPB) {
        int p = b >> 6, g = b & 63;
        int base = p * psize;
        int lim = n - base; if (lim > psize) lim = psize;
        int lim4 = (lim + 3) >> 2;
        for (int i = t; i < lim4; i += 1024) sm[i] = 0u;
        __syncthreads();
        // E % 4 == 0: every int4 batch is in-bounds and 16B-aligned.
        for (int e = (g * 1024 + t) * 4; e < E; e += GPB * 4096) {
            int4 r4 = *(const int4*)&row[e];
            int r0 = r4.x - base, r1 = r4.y - base, r2 = r4.z - base, r3 = r4.w - base;
            if ((unsigned)r0 < (unsigned)lim) atomicAdd(&sm[r0 >> 2], 1u << ((r0 & 3) * 8));
            if ((unsigned)r1 < (unsigned)lim) atomicAdd(&sm[r1 >> 2], 1u << ((r1 & 3) * 8));
            if ((unsigned)r2 < (unsigned)lim) atomicAdd(&sm[r2 >> 2], 1u << ((r2 & 3) * 8));
            if ((unsigned)r3 < (unsigned)lim) atomicAdd(&sm[r3 >> 2], 1u << ((r3 & 3) * 8));
        }
        __syncthreads();
        unsigned* dst = part + ((size_t)p * GPB + g) * psize4;
        for (int i = t; i < lim4; i += 1024) dst[i] = sm[i];
    } else {
        int cb = b - NPART * GPB;
        int* h = (int*)sm;
        for (int i = t; i < P; i += 1024) h[i] = 0;
        __syncthreads();
        int s = cb * CH, e = min(s + CH, E);   // multiples of 4 (CH % 4 == 0)
        for (int i = s + t * 4; i < e; i += 4096) {
            int4 c4 = *(const int4*)&col[i];
            atomicAdd(&h[c4.x >> 9], 1);
            atomicAdd(&h[c4.y >> 9], 1);
            atomicAdd(&h[c4.z >> 9], 1);
            atomicAdd(&h[c4.w >> 9], 1);
        }
        __syncthreads();
        for (int p = t; p < P; p += 1024) M[p * NB + cb] = h[p];
    }
}

// --- dis from u8 partials (4 nodes/thread) ∥ scan pass 1 ---
__global__ void k_ds1(const unsigned* __restrict__ part, float* __restrict__ dis,
                      int* __restrict__ M, int* __restrict__ bsum,
                      int n, int psize4, int ndis4, int P) {
    __shared__ int sc[256];
    int t = threadIdx.x, b = blockIdx.x;
    if (b < ndis4) {
        int i4 = b * 256 + t;
        int i = i4 * 4;
        if (i >= n) return;
        int p = i4 / psize4, loc = i4 - p * psize4;
        const unsigned* src = part + (size_t)p * GPB * psize4 + loc;
        unsigned s0 = 0, s1 = 0, s2 = 0, s3 = 0;
        #pragma unroll 8
        for (int g = 0; g < GPB; ++g) {
            unsigned u = src[(size_t)g * psize4];
            s0 += u & 255u; s1 += (u >> 8) & 255u;
            s2 += (u >> 16) & 255u; s3 += u >> 24;
        }
        dis[i] = rsqrtf((float)s0 + 1.0f);
        if (i + 1 < n) dis[i + 1] = rsqrtf((float)s1 + 1.0f);
        if (i + 2 < n) dis[i + 2] = rsqrtf((float)s2 + 1.0f);
        if (i + 3 < n) dis[i + 3] = rsqrtf((float)s3 + 1.0f);
    } else {
        int sb = b - ndis4;
        int i = sb * 256 + t;
        int v = M[i];
        sc[t] = v;
        __syncthreads();
        for (int d = 1; d < 256; d <<= 1) {
            int u = (t >= d) ? sc[t - d] : 0;
            __syncthreads(); sc[t] += u; __syncthreads();
        }
        M[i] = sc[t] - v;
        if (t == 255) bsum[sb] = sc[255];
    }
}

// --- coarse scatter, 1024 threads, int4 sweep (scan guarded to t<256) ---
__global__ __launch_bounds__(1024)
void k_csc(const int* __restrict__ row, const int* __restrict__ col,
           const int* __restrict__ M, const int* __restrict__ bsum,
           int* __restrict__ s4, int E, int CH, int P) {
    __shared__ int sc[256];
    __shared__ int bs[256];
    __shared__ int cur[MAXP];
    int t = threadIdx.x, b = blockIdx.x;
    if (t < 256) { int v = (t < P) ? bsum[t] : 0; sc[t] = v; bs[t] = v; }
    __syncthreads();
    for (int d = 1; d < 256; d <<= 1) {
        int u = (t < 256 && t >= d) ? sc[t - d] : 0;
        __syncthreads();
        if (t < 256) sc[t] += u;
        __syncthreads();
    }
    if (t < 256) bs[t] = sc[t] - bs[t];
    __syncthreads();
    for (int p = t; p < P; p += 1024) cur[p] = bs[p] + M[p * NB + b];
    __syncthreads();
    int s = b * CH, e = min(s + CH, E);   // multiples of 4
    for (int i = s + t * 4; i < e; i += 4096) {
        int4 r4 = *(const int4*)&row[i];
        int4 c4 = *(const int4*)&col[i];
        int p0 = atomicAdd(&cur[c4.x >> 9], 1);
        s4[p0] = (r4.x << 9) | (c4.x & 511);
        int p1 = atomicAdd(&cur[c4.y >> 9], 1);
        s4[p1] = (r4.y << 9) | (c4.y & 511);
        int p2 = atomicAdd(&cur[c4.z >> 9], 1);
        s4[p2] = (r4.z << 9) | (c4.z & 511);
        int p3 = atomicAdd(&cur[c4.w >> 9], 1);
        s4[p3] = (r4.w << 9) | (c4.w & 511);
    }
}

// --- fine counting sort, 1024 threads (scans guarded to t<256) ---
__global__ __launch_bounds__(1024)
void k_fsort(const int* __restrict__ s4, const int* __restrict__ bsum,
             int* __restrict__ rows4, int* __restrict__ off,
             int n, int E, int P) {
    __shared__ int sc[256];
    __shared__ int bs[256];
    __shared__ int hist[BW];
    __shared__ int loff[BW];
    __shared__ int tmp[256];
    int t = threadIdx.x, b = blockIdx.x;
    if (t < 256) { int v = (t < P) ? bsum[t] : 0; sc[t] = v; bs[t] = v; }
    __syncthreads();
    for (int d = 1; d < 256; d <<= 1) {
        int u = (t < 256 && t >= d) ? sc[t - d] : 0;
        __syncthreads();
        if (t < 256) sc[t] += u;
        __syncthreads();
    }
    if (t < 256) bs[t] = sc[t] - bs[t];
    __syncthreads();
    int gs = bs[b];
    int ge = gs + bsum[b];
    int c0 = b << 9;
    int lim = n - c0; if (lim > BW) lim = BW;
    for (int i = t; i < BW; i += 1024) hist[i] = 0;
    __syncthreads();
    for (int i = gs + t; i < ge; i += 1024)
        atomicAdd(&hist[s4[i] & 511], 1);
    __syncthreads();
    int s0 = 0, s1v = 0, ps = 0;
    if (t < 256) {
        s0 = hist[2 * t]; s1v = hist[2 * t + 1];
        ps = s0 + s1v;
        tmp[t] = ps;
    }
    __syncthreads();
    for (int d = 1; d < 256; d <<= 1) {
        int u = (t < 256 && t >= d) ? tmp[t - d] : 0;
        __syncthreads();
        if (t < 256) tmp[t] += u;
        __syncthreads();
    }
    if (t < 256) {
        int ex = tmp[t] - ps;
        loff[2 * t] = ex;
        loff[2 * t + 1] = ex + s0;
    }
    __syncthreads();
    for (int i = t; i < lim; i += 1024) off[c0 + i] = gs + loff[i];
    if (b == P - 1 && t == 0) off[n] = E;
    __syncthreads();
    for (int i = gs + t; i < ge; i += 1024) {
        int v2 = s4[i];
        int pos = gs + atomicAdd(&loff[v2 & 511], 1);
        rows4[pos] = v2 >> 9;
    }
}

// --- linear layer 1: g1 = bf16(dis*(concat(x,feat)@W1+b1)), slab layout ---
__global__ __launch_bounds__(256, 4)
void k_linc(const float* __restrict__ x, const float* __restrict__ feat,
            const float* __restrict__ W, const float* __restrict__ bvec,
            const float* __restrict__ dis, bf16* __restrict__ g1, int n) {
    __shared__ float sIn[4][FDIM];
    int t = threadIdx.x;
    int local = t >> 6, j = t & 63;
    float Wreg[FDIM];
    #pragma unroll
    for (int k = 0; k < FDIM; ++k) Wreg[k] = W[k * FDIM + j];
    float bj = bvec[j];
    int slab = j >> 4, jo = j & 15;
    int gw = blockIdx.x * 4 + local;
    int nwl = GPLIN * 4;
    for (int w = gw; w < n; w += nwl) {
        sIn[local][j] = (j < 32) ? x[(size_t)w * 32 + j]
                                 : feat[(size_t)w * 32 + (j - 32)];
        __threadfence_block();
        float o = bj;
        #pragma unroll
        for (int k4 = 0; k4 < 16; ++k4) {
            float4 h4 = *(const float4*)&sIn[local][k4 * 4];
            o = fmaf(h4.x, Wreg[4 * k4 + 0], o);
            o = fmaf(h4.y, Wreg[4 * k4 + 1], o);
            o = fmaf(h4.z, Wreg[4 * k4 + 2], o);
            o = fmaf(h4.w, Wreg[4 * k4 + 3], o);
        }
        g1[(size_t)slab * n * 16 + (size_t)w * 16 + jo] =
            __float2bfloat16(dis[w] * o);
        __threadfence_block();
    }
}

// --- slab gather: a[w][j] = relu(dis[w]*(g[w][j]+Σ g[r][j])), [4][n][16].
// Pass p (grid segment) = slab p, 3.2 MB -> per-XCD-L2-resident. Wave = 1
// node; lane (es=lane>>3, j2=lane&7): 8 edges x ushort2 = 256 B/instr.
// rows4 + a-writes non-temporal so the slab owns L2.
__global__ __launch_bounds__(256, 8)
void k_gather(const int* __restrict__ rows4, const int* __restrict__ off,
              const float* __restrict__ dis, const bf16* __restrict__ g,
              bf16* __restrict__ a, int n, int nbp) {
    int b = blockIdx.x;
    int pass = b / nbp;                 // 0..3 (slab id)
    int bb = b - pass * nbp;
    int w = bb * 4 + (threadIdx.x >> 6);
    if (w >= n) return;
    int lane = threadIdx.x & 63;
    int es = lane >> 3;                 // edge sub-slot 0..7
    int j2 = lane & 7;                  // feature pair of the slab
    const unsigned* gs = (const unsigned*)g + (size_t)pass * n * 8;
    unsigned* as = (unsigned*)a + (size_t)pass * n * 8;
    float acc0 = 0.0f, acc1 = 0.0f;
    int s = off[w], e = off[w + 1];
    int k = s;
    for (; k + 8 <= e; k += 8) {
        int r = __builtin_nontemporal_load(rows4 + k + es);
        unsigned u = gs[(size_t)r * 8 + j2];
        acc0 += ulo2f(u);
        acc1 += uhi2f(u);
    }
    if (k < e) {
        int idx = k + es;
        int r = __builtin_nontemporal_load(rows4 + min(idx, e - 1));
        unsigned u = gs[(size_t)r * 8 + j2];
        float wg = (idx < e) ? 1.0f : 0.0f;
        acc0 = fmaf(wg, ulo2f(u), acc0);
        acc1 = fmaf(wg, uhi2f(u), acc1);
    }
    #pragma unroll
    for (int m = 8; m <= 32; m <<= 1) {
        acc0 += __shfl_xor(acc0, m, 64);
        acc1 += __shfl_xor(acc1, m, 64);
    }
    if (es == 0) {
        unsigned su = gs[(size_t)w * 8 + j2];      // self loop
        float dv = dis[w];
        float v0 = fmaxf(dv * (acc0 + ulo2f(su)), 0.0f);
        float v1 = fmaxf(dv * (acc1 + uhi2f(su)), 0.0f);
        __builtin_nontemporal_store(f2bu(v0) | (f2bu(v1) << 16),
                                    as + (size_t)w * 8 + j2);
    }
}

// --- MFMA matvec: o = A@W + b ; FINAL ? relu(o) f32 : slab bf16(dis*o) ---
// A layout [4][n][16]: af0 = feats quad*8.. -> slab quad>>1, half quad&1;
// af1 = feats 32+quad*8 -> slab 2+(quad>>1). All v8s 16B-aligned.
template <bool FINAL>
__global__ __launch_bounds__(256, 4)
void k_mat(const bf16* __restrict__ A, const float* __restrict__ W,
           const float* __restrict__ bvec, const float* __restrict__ dis,
           void* __restrict__ outp, int n) {
    __shared__ __align__(16) bf16 sWt[FDIM * FDIM];   // Wt[n][k] (transposed)
    int t = threadIdx.x;
    for (int idx = t; idx < FDIM * FDIM; idx += 256) {
        int kk = idx >> 6, nn = idx & 63;
        sWt[nn * FDIM + kk] = __float2bfloat16(W[idx]);
    }
    __syncthreads();
    int wave = t >> 6, lane = t & 63;
    int quad = lane >> 4, l15 = lane & 15;
    v8s bfr[4][2];
    #pragma unroll
    for (int nt = 0; nt < 4; ++nt) {
        #pragma unroll
        for (int kf = 0; kf < 2; ++kf)
            bfr[nt][kf] = *(const v8s*)&sWt[(nt * 16 + l15) * FDIM + kf * 32 + quad * 8];
    }
    float bj[4];
    #pragma unroll
    for (int nt = 0; nt < 4; ++nt) bj[nt] = bvec[nt * 16 + l15];

    const bf16* A0 = A + (size_t)(quad >> 1) * n * 16;
    const bf16* A1 = A + (size_t)(2 + (quad >> 1)) * n * 16;
    int ho = (quad & 1) * 8;

    int ntiles = (n + 15) >> 4;
    int step = gridDim.x * 4;
    for (int tile = blockIdx.x * 4 + wave; tile < ntiles; tile += step) {
        int m0 = tile << 4;
        int mA = m0 + l15; if (mA >= n) mA = n - 1;
        v8s af0 = *(const v8s*)&A0[(size_t)mA * 16 + ho];
        v8s af1 = *(const v8s*)&A1[(size_t)mA * 16 + ho];
        v4f acc[4];
        #pragma unroll
        for (int nt = 0; nt < 4; ++nt) {
            acc[nt] = (v4f){0.f, 0.f, 0.f, 0.f};
            acc[nt] = __builtin_amdgcn_mfma_f32_16x16x32_bf16(af0, bfr[nt][0], acc[nt], 0, 0, 0);
            acc[nt] = __builtin_amdgcn_mfma_f32_16x16x32_bf16(af1, bfr[nt][1], acc[nt], 0, 0, 0);
        }
        #pragma unroll
        for (int r = 0; r < 4; ++r) {
            int node = m0 + quad * 4 + r;
            if (node >= n) continue;
            float dv = FINAL ? 0.0f : dis[node];
            #pragma unroll
            for (int nt = 0; nt < 4; ++nt) {
                int j = nt * 16 + l15;
                float o = acc[nt][r] + bj[nt];
                if (FINAL) {
                    ((float*)outp)[(size_t)node * FDIM + j] = fmaxf(o, 0.0f);
                } else {
                    // slab = nt (l15 < 16), offset l15
                    ((bf16*)outp)[(size_t)nt * n * 16 + (size_t)node * 16 + l15] =
                        __float2bfloat16(dv * o);
                }
            }
        }
    }
}

extern "C" void kernel_launch(void* const* d_in, const int* in_sizes, int n_in,
                              void* d_out, int out_size, void* d_ws, size_t ws_size,
                              hipStream_t stream) {
    const float* x    = (const float*)d_in[0];
    const float* feat = (const float*)d_in[1];
    const int*   ei   = (const int*)d_in[2];
    const float* W1   = (const float*)d_in[3];
    const float* b1   = (const float*)d_in[4];
    const float* W2   = (const float*)d_in[5];
    const float* b2   = (const float*)d_in[6];
    const float* Wfc  = (const float*)d_in[7];
    const float* bfc  = (const float*)d_in[8];
    float* out = (float*)d_out;

    const int n = in_sizes[0] / 32;   // 100000
    const int E = in_sizes[2] / 2;    // 1600000 (multiple of 4)
    const int* row = ei;
    const int* col = ei + E;

    const int psize = (((n + NPART - 1) / NPART) + 3) & ~3;   // 25000
    const int psize4 = psize >> 2;                            // 6250
    const int P  = (n + BW - 1) / BW;                         // 196
    const int CH = (((E + NB - 1) / NB) + 3) & ~3;            // 6252 (x4 aligned)
    const int total = P * NB;                                 // 50176
    const int ndis4 = (((n + 3) / 4) + 255) / 256;            // 98
    const int nbp = (n + 3) / 4;                              // 25000 blocks/pass

    // ws: off[n+1] | dis[n] | M[total] | bsum[256] | s4[E] | rows4[E]
    //     | (16B-aligned) bufA(bf16 64n) | bufB(bf16 64n)
    // part (NPART*GPB*psize4 u32 = 6.4 MB) aliases bufA (consumed in k_ds1
    // before k_linc writes g1 into bufA).
    int*   off  = (int*)d_ws;
    float* dis  = (float*)(off + (size_t)n + 1);
    int*   M    = (int*)(dis + n);
    int*   bsum = M + (size_t)total;
    int*   s4    = bsum + 256;
    int*   rows4 = s4 + E;
    size_t co = (size_t)(rows4 + E - (int*)d_ws);
    co = (co + 3) & ~(size_t)3;                  // 16B align for v8s loads
    bf16*  bufA  = (bf16*)((int*)d_ws + co);
    bf16*  bufB  = bufA + (size_t)n * FDIM;
    unsigned* part = (unsigned*)bufA;

    k_h2<<<NPART * GPB + NB, 1024, 0, stream>>>(row, col, part, M, E, n,
                                                psize, psize4, P, CH);
    k_ds1<<<ndis4 + P, 256, 0, stream>>>(part, dis, M, bsum, n, psize4, ndis4, P);
    k_csc<<<NB, 1024, 0, stream>>>(row, col, M, bsum, s4, E, CH, P);
    k_fsort<<<P, 1024, 0, stream>>>(s4, bsum, rows4, off, n, E, P);
    k_linc<<<GPLIN, 256, 0, stream>>>(x, feat, W1, b1, dis, bufA, n);
    // layer 2: gather(g1)->a1 ; mat: g2 = slab-bf16(dis*(a1@W2+b2))
    k_gather<<<4 * nbp, 256, 0, stream>>>(rows4, off, dis, bufA, bufB, n, nbp);
    k_mat<false><<<512, 256, 0, stream>>>(bufB, W2, b2, dis, bufA, n);
    // fc: gather(g2)->a2 ; out = relu(a2@Wfc+bfc)
    k_gather<<<4 * nbp, 256, 0, stream>>>(rows4, off, dis, bufA, bufB, n, nbp);
    k_mat<true><<<512, 256, 0, stream>>>(bufB, Wfc, bfc, dis, out, n);
}

// Round 13
// 334.003 us; speedup vs baseline: 1.4938x; 1.4938x over previous
//
#include <hip/hip_runtime.h>
#include <hip/hip_bf16.h>

// GCN v23 — slab-16 gather, MLP restored via 4-node-interleaved waves.
//   r22 post-mortem: slab residency CONFIRMED (FETCH 156->85.5 MB) but dur
//   161.7 us: loop had 1 serial rows4->g load/iter (VGPR=8, MLP~1 — the
//   v13/v20 failure re-triggered), plus 32B partial-line NT stores doubled
//   WRITE (13.6->28.4 MB). v23 keeps [4][n][16] slabs; each wave owns 4
//   consecutive nodes, chunk loop to max(deg_i) issues 4 rows4 + 4 g loads
//   per iter (8 in flight, v14-class MLP); tails zero-weighted (clamped dup
//   loads hit resident lines). Finalize: lanes 0-31 write 4x32B = one
//   coalesced 128B NT store. Pre-committed falsification: gather > 50 us
//   -> revert to v21, gather declared at wall.
//   Build kernels byte-identical to v21; k_linc/k_mat slab forms from v22
//   (correctness-proven).

#define FDIM 64
#define NPART 4
#define GPB 64
#define NB 256
#define BW 512
#define MAXP 1024
#define GPLIN 1024

typedef __hip_bfloat16 bf16;
typedef short v8s __attribute__((ext_vector_type(8)));
typedef float v4f __attribute__((ext_vector_type(4)));

static __device__ __forceinline__ float ulo2f(unsigned u) {
    union { unsigned x; float f; } v; v.x = u << 16; return v.f;
}
static __device__ __forceinline__ float uhi2f(unsigned u) {
    union { unsigned x; float f; } v; v.x = u & 0xFFFF0000u; return v.f;
}
static __device__ __forceinline__ unsigned f2bu(float f) {
    bf16 b = __float2bfloat16(f);
    return (unsigned)(*(unsigned short*)&b);
}

// --- dispatch 1: deg u8 partial hist (b < NPART*GPB) ∥ col coarse hist ---
__global__ __launch_bounds__(1024)
void k_h2(const int* __restrict__ row, const int* __restrict__ col,
          unsigned* __restrict__ part, int* __restrict__ M,
          int E, int n, int psize, int psize4, int P, int CH) {
    __shared__ unsigned sm[6256];
    int t = threadIdx.x, b = blockIdx.x;
    if (b < NPART * GPB) {
        int p = b >> 6, g = b & 63;
        int base = p * psize;
        int lim = n - base; if (lim > psize) lim = psize;
        int lim4 = (lim + 3) >> 2;
        for (int i = t; i < lim4; i += 1024) sm[i] = 0u;
        __syncthreads();
        // E % 4 == 0: every int4 batch is in-bounds and 16B-aligned.
        for (int e = (g * 1024 + t) * 4; e < E; e += GPB * 4096) {
            int4 r4 = *(const int4*)&row[e];
            int r0 = r4.x - base, r1 = r4.y - base, r2 = r4.z - base, r3 = r4.w - base;
            if ((unsigned)r0 < (unsigned)lim) atomicAdd(&sm[r0 >> 2], 1u << ((r0 & 3) * 8));
            if ((unsigned)r1 < (unsigned)lim) atomicAdd(&sm[r1 >> 2], 1u << ((r1 & 3) * 8));
            if ((unsigned)r2 < (unsigned)lim) atomicAdd(&sm[r2 >> 2], 1u << ((r2 & 3) * 8));
            if ((unsigned)r3 < (unsigned)lim) atomicAdd(&sm[r3 >> 2], 1u << ((r3 & 3) * 8));
        }
        __syncthreads();
        unsigned* dst = part + ((size_t)p * GPB + g) * psize4;
        for (int i = t; i < lim4; i += 1024) dst[i] = sm[i];
    } else {
        int cb = b - NPART * GPB;
        int* h = (int*)sm;
        for (int i = t; i < P; i += 1024) h[i] = 0;
        __syncthreads();
        int s = cb * CH, e = min(s + CH, E);   // multiples of 4 (CH % 4 == 0)
        for (int i = s + t * 4; i < e; i += 4096) {
            int4 c4 = *(const int4*)&col[i];
            atomicAdd(&h[c4.x >> 9], 1);
            atomicAdd(&h[c4.y >> 9], 1);
            atomicAdd(&h[c4.z >> 9], 1);
            atomicAdd(&h[c4.w >> 9], 1);
        }
        __syncthreads();
        for (int p = t; p < P; p += 1024) M[p * NB + cb] = h[p];
    }
}

// --- dis from u8 partials (4 nodes/thread) ∥ scan pass 1 ---
__global__ void k_ds1(const unsigned* __restrict__ part, float* __restrict__ dis,
                      int* __restrict__ M, int* __restrict__ bsum,
                      int n, int psize4, int ndis4, int P) {
    __shared__ int sc[256];
    int t = threadIdx.x, b = blockIdx.x;
    if (b < ndis4) {
        int i4 = b * 256 + t;
        int i = i4 * 4;
        if (i >= n) return;
        int p = i4 / psize4, loc = i4 - p * psize4;
        const unsigned* src = part + (size_t)p * GPB * psize4 + loc;
        unsigned s0 = 0, s1 = 0, s2 = 0, s3 = 0;
        #pragma unroll 8
        for (int g = 0; g < GPB; ++g) {
            unsigned u = src[(size_t)g * psize4];
            s0 += u & 255u; s1 += (u >> 8) & 255u;
            s2 += (u >> 16) & 255u; s3 += u >> 24;
        }
        dis[i] = rsqrtf((float)s0 + 1.0f);
        if (i + 1 < n) dis[i + 1] = rsqrtf((float)s1 + 1.0f);
        if (i + 2 < n) dis[i + 2] = rsqrtf((float)s2 + 1.0f);
        if (i + 3 < n) dis[i + 3] = rsqrtf((float)s3 + 1.0f);
    } else {
        int sb = b - ndis4;
        int i = sb * 256 + t;
        int v = M[i];
        sc[t] = v;
        __syncthreads();
        for (int d = 1; d < 256; d <<= 1) {
            int u = (t >= d) ? sc[t - d] : 0;
            __syncthreads(); sc[t] += u; __syncthreads();
        }
        M[i] = sc[t] - v;
        if (t == 255) bsum[sb] = sc[255];
    }
}

// --- coarse scatter, 1024 threads, int4 sweep (scan guarded to t<256) ---
__global__ __launch_bounds__(1024)
void k_csc(const int* __restrict__ row, const int* __restrict__ col,
           const int* __restrict__ M, const int* __restrict__ bsum,
           int* __restrict__ s4, int E, int CH, int P) {
    __shared__ int sc[256];
    __shared__ int bs[256];
    __shared__ int cur[MAXP];
    int t = threadIdx.x, b = blockIdx.x;
    if (t < 256) { int v = (t < P) ? bsum[t] : 0; sc[t] = v; bs[t] = v; }
    __syncthreads();
    for (int d = 1; d < 256; d <<= 1) {
        int u = (t < 256 && t >= d) ? sc[t - d] : 0;
        __syncthreads();
        if (t < 256) sc[t] += u;
        __syncthreads();
    }
    if (t < 256) bs[t] = sc[t] - bs[t];
    __syncthreads();
    for (int p = t; p < P; p += 1024) cur[p] = bs[p] + M[p * NB + b];
    __syncthreads();
    int s = b * CH, e = min(s + CH, E);   // multiples of 4
    for (int i = s + t * 4; i < e; i += 4096) {
        int4 r4 = *(const int4*)&row[i];
        int4 c4 = *(const int4*)&col[i];
        int p0 = atomicAdd(&cur[c4.x >> 9], 1);
        s4[p0] = (r4.x << 9) | (c4.x & 511);
        int p1 = atomicAdd(&cur[c4.y >> 9], 1);
        s4[p1] = (r4.y << 9) | (c4.y & 511);
        int p2 = atomicAdd(&cur[c4.z >> 9], 1);
        s4[p2] = (r4.z << 9) | (c4.z & 511);
        int p3 = atomicAdd(&cur[c4.w >> 9], 1);
        s4[p3] = (r4.w << 9) | (c4.w & 511);
    }
}

// --- fine counting sort, 1024 threads (scans guarded to t<256) ---
__global__ __launch_bounds__(1024)
void k_fsort(const int* __restrict__ s4, const int* __restrict__ bsum,
             int* __restrict__ rows4, int* __restrict__ off,
             int n, int E, int P) {
    __shared__ int sc[256];
    __shared__ int bs[256];
    __shared__ int hist[BW];
    __shared__ int loff[BW];
    __shared__ int tmp[256];
    int t = threadIdx.x, b = blockIdx.x;
    if (t < 256) { int v = (t < P) ? bsum[t] : 0; sc[t] = v; bs[t] = v; }
    __syncthreads();
    for (int d = 1; d < 256; d <<= 1) {
        int u = (t < 256 && t >= d) ? sc[t - d] : 0;
        __syncthreads();
        if (t < 256) sc[t] += u;
        __syncthreads();
    }
    if (t < 256) bs[t] = sc[t] - bs[t];
    __syncthreads();
    int gs = bs[b];
    int ge = gs + bsum[b];
    int c0 = b << 9;
    int lim = n - c0; if (lim > BW) lim = BW;
    for (int i = t; i < BW; i += 1024) hist[i] = 0;
    __syncthreads();
    for (int i = gs + t; i < ge; i += 1024)
        atomicAdd(&hist[s4[i] & 511], 1);
    __syncthreads();
    int s0 = 0, s1v = 0, ps = 0;
    if (t < 256) {
        s0 = hist[2 * t]; s1v = hist[2 * t + 1];
        ps = s0 + s1v;
        tmp[t] = ps;
    }
    __syncthreads();
    for (int d = 1; d < 256; d <<= 1) {
        int u = (t < 256 && t >= d) ? tmp[t - d] : 0;
        __syncthreads();
        if (t < 256) tmp[t] += u;
        __syncthreads();
    }
    if (t < 256) {
        int ex = tmp[t] - ps;
        loff[2 * t] = ex;
        loff[2 * t + 1] = ex + s0;
    }
    __syncthreads();
    for (int i = t; i < lim; i += 1024) off[c0 + i] = gs + loff[i];
    if (b == P - 1 && t == 0) off[n] = E;
    __syncthreads();
    for (int i = gs + t; i < ge; i += 1024) {
        int v2 = s4[i];
        int pos = gs + atomicAdd(&loff[v2 & 511], 1);
        rows4[pos] = v2 >> 9;
    }
}

// --- linear layer 1: g1 = bf16(dis*(concat(x,feat)@W1+b1)), slab layout ---
__global__ __launch_bounds__(256, 4)
void k_linc(const float* __restrict__ x, const float* __restrict__ feat,
            const float* __restrict__ W, const float* __restrict__ bvec,
            const float* __restrict__ dis, bf16* __restrict__ g1, int n) {
    __shared__ float sIn[4][FDIM];
    int t = threadIdx.x;
    int local = t >> 6, j = t & 63;
    float Wreg[FDIM];
    #pragma unroll
    for (int k = 0; k < FDIM; ++k) Wreg[k] = W[k * FDIM + j];
    float bj = bvec[j];
    int slab = j >> 4, jo = j & 15;
    int gw = blockIdx.x * 4 + local;
    int nwl = GPLIN * 4;
    for (int w = gw; w < n; w += nwl) {
        sIn[local][j] = (j < 32) ? x[(size_t)w * 32 + j]
                                 : feat[(size_t)w * 32 + (j - 32)];
        __threadfence_block();
        float o = bj;
        #pragma unroll
        for (int k4 = 0; k4 < 16; ++k4) {
            float4 h4 = *(const float4*)&sIn[local][k4 * 4];
            o = fmaf(h4.x, Wreg[4 * k4 + 0], o);
            o = fmaf(h4.y, Wreg[4 * k4 + 1], o);
            o = fmaf(h4.z, Wreg[4 * k4 + 2], o);
            o = fmaf(h4.w, Wreg[4 * k4 + 3], o);
        }
        g1[(size_t)slab * n * 16 + (size_t)w * 16 + jo] =
            __float2bfloat16(dis[w] * o);
        __threadfence_block();
    }
}

// --- slab gather, 4-node interleave: a[w][j]=relu(dis[w]*(g[w][j]+Σ g[r][j])).
// Layout [4][n][16]. Grid: 4 pass-segments (slab p = 3.2 MB, L2-resident).
// Wave = 4 consecutive nodes x 1 slab; lane (es=lane>>3, j2=lane&7).
// Chunk loop to max(deg_i): 4 rows4 + 4 g loads per iter -> 8 in flight.
// Tail slots zero-weighted (clamped dups hit resident lines). Finalize:
// lanes 0-31 write 4 nodes x 32 B = one coalesced 128 B NT store.
__global__ __launch_bounds__(256, 8)
void k_gather(const int* __restrict__ rows4, const int* __restrict__ off,
              const float* __restrict__ dis, const bf16* __restrict__ g,
              bf16* __restrict__ a, int n, int nbp) {
    int b = blockIdx.x;
    int pass = b / nbp;                 // 0..3 (slab id)
    int bb = b - pass * nbp;
    int wv = threadIdx.x >> 6;
    int w0 = (bb * 4 + wv) * 4;         // first of this wave's 4 nodes
    if (w0 >= n) return;
    int lane = threadIdx.x & 63;
    int es = lane >> 3;                 // edge sub-slot 0..7
    int j2 = lane & 7;                  // feature pair of the slab
    const unsigned* gs = (const unsigned*)g + (size_t)pass * n * 8;
    unsigned* as = (unsigned*)a + (size_t)pass * n * 8;
    int s[4], e[4];
    #pragma unroll
    for (int i = 0; i < 4; ++i) {
        int w = min(w0 + i, n - 1);     // dup node n-1 for tail; store guarded
        s[i] = off[w]; e[i] = off[w + 1];
    }
    int maxlen = 0;
    #pragma unroll
    for (int i = 0; i < 4; ++i) maxlen = max(maxlen, e[i] - s[i]);
    float a0[4] = {0.f, 0.f, 0.f, 0.f}, a1[4] = {0.f, 0.f, 0.f, 0.f};
    for (int k = 0; k < maxlen; k += 8) {
        #pragma unroll
        for (int i = 0; i < 4; ++i) {
            int idx = s[i] + k + es;
            // clamp: may touch rows4[-1] (= s4 tail, valid ws mem) iff deg==0
            int r = __builtin_nontemporal_load(rows4 + min(idx, e[i] - 1));
            unsigned u = gs[(size_t)r * 8 + j2];
            float wg = (idx < e[i]) ? 1.0f : 0.0f;
            a0[i] = fmaf(wg, ulo2f(u), a0[i]);
            a1[i] = fmaf(wg, uhi2f(u), a1[i]);
        }
    }
    #pragma unroll
    for (int m = 8; m <= 32; m <<= 1) {
        #pragma unroll
        for (int i = 0; i < 4; ++i) {
            a0[i] += __shfl_xor(a0[i], m, 64);
            a1[i] += __shfl_xor(a1[i], m, 64);
        }
    }
    if (lane < 32) {
        int i = lane >> 3, jj = lane & 7;
        int w = w0 + i;
        if (w < n) {
            unsigned su = gs[(size_t)w * 8 + jj];      // self loop
            float dv = dis[w];
            float v0 = fmaxf(dv * (a0[i] + ulo2f(su)), 0.0f);
            float v1 = fmaxf(dv * (a1[i] + uhi2f(su)), 0.0f);
            __builtin_nontemporal_store(f2bu(v0) | (f2bu(v1) << 16),
                                        as + (size_t)w * 8 + jj);
        }
    }
}

// --- MFMA matvec: o = A@W + b ; FINAL ? relu(o) f32 : slab bf16(dis*o) ---
// A layout [4][n][16]: af0 = feats quad*8.. -> slab quad>>1, half quad&1;
// af1 = feats 32+quad*8 -> slab 2+(quad>>1). All v8s 16B-aligned.
template <bool FINAL>
__global__ __launch_bounds__(256, 4)
void k_mat(const bf16* __restrict__ A, const float* __restrict__ W,
           const float* __restrict__ bvec, const float* __restrict__ dis,
           void* __restrict__ outp, int n) {
    __shared__ __align__(16) bf16 sWt[FDIM * FDIM];   // Wt[n][k] (transposed)
    int t = threadIdx.x;
    for (int idx = t; idx < FDIM * FDIM; idx += 256) {
        int kk = idx >> 6, nn = idx & 63;
        sWt[nn * FDIM + kk] = __float2bfloat16(W[idx]);
    }
    __syncthreads();
    int wave = t >> 6, lane = t & 63;
    int quad = lane >> 4, l15 = lane & 15;
    v8s bfr[4][2];
    #pragma unroll
    for (int nt = 0; nt < 4; ++nt) {
        #pragma unroll
        for (int kf = 0; kf < 2; ++kf)
            bfr[nt][kf] = *(const v8s*)&sWt[(nt * 16 + l15) * FDIM + kf * 32 + quad * 8];
    }
    float bj[4];
    #pragma unroll
    for (int nt = 0; nt < 4; ++nt) bj[nt] = bvec[nt * 16 + l15];

    const bf16* A0 = A + (size_t)(quad >> 1) * n * 16;
    const bf16* A1 = A + (size_t)(2 + (quad >> 1)) * n * 16;
    int ho = (quad & 1) * 8;

    int ntiles = (n + 15) >> 4;
    int step = gridDim.x * 4;
    for (int tile = blockIdx.x * 4 + wave; tile < ntiles; tile += step) {
        int m0 = tile << 4;
        int mA = m0 + l15; if (mA >= n) mA = n - 1;
        v8s af0 = *(const v8s*)&A0[(size_t)mA * 16 + ho];
        v8s af1 = *(const v8s*)&A1[(size_t)mA * 16 + ho];
        v4f acc[4];
        #pragma unroll
        for (int nt = 0; nt < 4; ++nt) {
            acc[nt] = (v4f){0.f, 0.f, 0.f, 0.f};
            acc[nt] = __builtin_amdgcn_mfma_f32_16x16x32_bf16(af0, bfr[nt][0], acc[nt], 0, 0, 0);
            acc[nt] = __builtin_amdgcn_mfma_f32_16x16x32_bf16(af1, bfr[nt][1], acc[nt], 0, 0, 0);
        }
        #pragma unroll
        for (int r = 0; r < 4; ++r) {
            int node = m0 + quad * 4 + r;
            if (node >= n) continue;
            float dv = FINAL ? 0.0f : dis[node];
            #pragma unroll
            for (int nt = 0; nt < 4; ++nt) {
                int j = nt * 16 + l15;
                float o = acc[nt][r] + bj[nt];
                if (FINAL) {
                    ((float*)outp)[(size_t)node * FDIM + j] = fmaxf(o, 0.0f);
                } else {
                    // slab = nt (l15 < 16), offset l15
                    ((bf16*)outp)[(size_t)nt * n * 16 + (size_t)node * 16 + l15] =
                        __float2bfloat16(dv * o);
                }
            }
        }
    }
}

extern "C" void kernel_launch(void* const* d_in, const int* in_sizes, int n_in,
                              void* d_out, int out_size, void* d_ws, size_t ws_size,
                              hipStream_t stream) {
    const float* x    = (const float*)d_in[0];
    const float* feat = (const float*)d_in[1];
    const int*   ei   = (const int*)d_in[2];
    const float* W1   = (const float*)d_in[3];
    const float* b1   = (const float*)d_in[4];
    const float* W2   = (const float*)d_in[5];
    const float* b2   = (const float*)d_in[6];
    const float* Wfc  = (const float*)d_in[7];
    const float* bfc  = (const float*)d_in[8];
    float* out = (float*)d_out;

    const int n = in_sizes[0] / 32;   // 100000
    const int E = in_sizes[2] / 2;    // 1600000 (multiple of 4)
    const int* row = ei;
    const int* col = ei + E;

    const int psize = (((n + NPART - 1) / NPART) + 3) & ~3;   // 25000
    const int psize4 = psize >> 2;                            // 6250
    const int P  = (n + BW - 1) / BW;                         // 196
    const int CH = (((E + NB - 1) / NB) + 3) & ~3;            // 6252 (x4 aligned)
    const int total = P * NB;                                 // 50176
    const int ndis4 = (((n + 3) / 4) + 255) / 256;            // 98
    const int nbp = (n + 15) / 16;                            // 6250 blocks/pass

    // ws: off[n+1] | dis[n] | M[total] | bsum[256] | s4[E] | rows4[E]
    //     | (16B-aligned) bufA(bf16 64n) | bufB(bf16 64n)
    // part (NPART*GPB*psize4 u32 = 6.4 MB) aliases bufA (consumed in k_ds1
    // before k_linc writes g1 into bufA).
    int*   off  = (int*)d_ws;
    float* dis  = (float*)(off + (size_t)n + 1);
    int*   M    = (int*)(dis + n);
    int*   bsum = M + (size_t)total;
    int*   s4    = bsum + 256;
    int*   rows4 = s4 + E;
    size_t co = (size_t)(rows4 + E - (int*)d_ws);
    co = (co + 3) & ~(size_t)3;                  // 16B align for v8s loads
    bf16*  bufA  = (bf16*)((int*)d_ws + co);
    bf16*  bufB  = bufA + (size_t)n * FDIM;
    unsigned* part = (unsigned*)bufA;

    k_h2<<<NPART * GPB + NB, 1024, 0, stream>>>(row, col, part, M, E, n,
                                                psize, psize4, P, CH);
    k_ds1<<<ndis4 + P, 256, 0, stream>>>(part, dis, M, bsum, n, psize4, ndis4, P);
    k_csc<<<NB, 1024, 0, stream>>>(row, col, M, bsum, s4, E, CH, P);
    k_fsort<<<P, 1024, 0, stream>>>(s4, bsum, rows4, off, n, E, P);
    k_linc<<<GPLIN, 256, 0, stream>>>(x, feat, W1, b1, dis, bufA, n);
    // layer 2: gather(g1)->a1 ; mat: g2 = slab-bf16(dis*(a1@W2+b2))
    k_gather<<<4 * nbp, 256, 0, stream>>>(rows4, off, dis, bufA, bufB, n, nbp);
    k_mat<false><<<512, 256, 0, stream>>>(bufB, W2, b2, dis, bufA, n);
    // fc: gather(g2)->a2 ; out = relu(a2@Wfc+bfc)
    k_gather<<<4 * nbp, 256, 0, stream>>>(rows4, off, dis, bufA, bufB, n, nbp);
    k_mat<true><<<512, 256, 0, stream>>>(bufB, Wfc, bfc, dis, out, n);
}

// Round 15
// 273.352 us; speedup vs baseline: 1.8253x; 1.2219x over previous
//
#include <hip/hip_runtime.h>
#include <hip/hip_bf16.h>

// GCN v24 — v21 full revert (proven 272.0 us) + NPART 4->2 in deg histogram.
//   r23 post-mortem: slab gather line CLOSED. FETCH cut confirmed twice
//   (156->81 MB) but dur rose (83 us @1.2 TB/s): slabbing multiplies L2
//   request count 4x (4 passes x 1.6M x 32B vs 1.6M x 128B) — the random
//   gather wall is REQUEST-rate-coupled. Full-row dual-edge gather (51 us,
//   93% of ceiling) is final. v24 = v21 byte-identical except the deg u8
//   partial histogram uses NPART=2 (psize=50000, 50 KB LDS, still
//   2 blocks/CU thread-limited): row re-read 4x -> 2x (-12.8 MB of
//   latency-bound L3 traffic in k_h2).
//   (r25 resubmit: round-14 bench was a container-acquisition flake, same
//    signature as rounds 1-2 which resolved on identical resubmission.
//    Diff vs proven v21 audited: no hang mechanism.)

#define FDIM 64
#define NPART 2
#define GPB 64
#define NB 256
#define BW 512
#define MAXP 1024
#define GPLIN 1024

typedef __hip_bfloat16 bf16;
typedef short v8s __attribute__((ext_vector_type(8)));
typedef float v4f __attribute__((ext_vector_type(4)));

static __device__ __forceinline__ float ulo2f(unsigned u) {
    union { unsigned x; float f; } v; v.x = u << 16; return v.f;
}
static __device__ __forceinline__ float uhi2f(unsigned u) {
    union { unsigned x; float f; } v; v.x = u & 0xFFFF0000u; return v.f;
}
static __device__ __forceinline__ unsigned f2bu(float f) {
    bf16 b = __float2bfloat16(f);
    return (unsigned)(*(unsigned short*)&b);
}

// --- dispatch 1: deg u8 partial hist (b < NPART*GPB) ∥ col coarse hist ---
__global__ __launch_bounds__(1024)
void k_h2(const int* __restrict__ row, const int* __restrict__ col,
          unsigned* __restrict__ part, int* __restrict__ M,
          int E, int n, int psize, int psize4, int P, int CH) {
    __shared__ unsigned sm[12512];
    int t = threadIdx.x, b = blockIdx.x;
    if (b < NPART * GPB) {
        int p = b >> 6, g = b & 63;
        int base = p * psize;
        int lim = n - base; if (lim > psize) lim = psize;
        int lim4 = (lim + 3) >> 2;
        for (int i = t; i < lim4; i += 1024) sm[i] = 0u;
        __syncthreads();
        // E % 4 == 0: every int4 batch is in-bounds and 16B-aligned.
        for (int e = (g * 1024 + t) * 4; e < E; e += GPB * 4096) {
            int4 r4 = *(const int4*)&row[e];
            int r0 = r4.x - base, r1 = r4.y - base, r2 = r4.z - base, r3 = r4.w - base;
            if ((unsigned)r0 < (unsigned)lim) atomicAdd(&sm[r0 >> 2], 1u << ((r0 & 3) * 8));
            if ((unsigned)r1 < (unsigned)lim) atomicAdd(&sm[r1 >> 2], 1u << ((r1 & 3) * 8));
            if ((unsigned)r2 < (unsigned)lim) atomicAdd(&sm[r2 >> 2], 1u << ((r2 & 3) * 8));
            if ((unsigned)r3 < (unsigned)lim) atomicAdd(&sm[r3 >> 2], 1u << ((r3 & 3) * 8));
        }
        __syncthreads();
        unsigned* dst = part + ((size_t)p * GPB + g) * psize4;
        for (int i = t; i < lim4; i += 1024) dst[i] = sm[i];
    } else {
        int cb = b - NPART * GPB;
        int* h = (int*)sm;
        for (int i = t; i < P; i += 1024) h[i] = 0;
        __syncthreads();
        int s = cb * CH, e = min(s + CH, E);   // multiples of 4 (CH % 4 == 0)
        for (int i = s + t * 4; i < e; i += 4096) {
            int4 c4 = *(const int4*)&col[i];
            atomicAdd(&h[c4.x >> 9], 1);
            atomicAdd(&h[c4.y >> 9], 1);
            atomicAdd(&h[c4.z >> 9], 1);
            atomicAdd(&h[c4.w >> 9], 1);
        }
        __syncthreads();
        for (int p = t; p < P; p += 1024) M[p * NB + cb] = h[p];
    }
}

// --- dis from u8 partials (4 nodes/thread) ∥ scan pass 1 ---
__global__ void k_ds1(const unsigned* __restrict__ part, float* __restrict__ dis,
                      int* __restrict__ M, int* __restrict__ bsum,
                      int n, int psize4, int ndis4, int P) {
    __shared__ int sc[256];
    int t = threadIdx.x, b = blockIdx.x;
    if (b < ndis4) {
        int i4 = b * 256 + t;
        int i = i4 * 4;
        if (i >= n) return;
        int p = i4 / psize4, loc = i4 - p * psize4;
        const unsigned* src = part + (size_t)p * GPB * psize4 + loc;
        unsigned s0 = 0, s1 = 0, s2 = 0, s3 = 0;
        #pragma unroll 8
        for (int g = 0; g < GPB; ++g) {
            unsigned u = src[(size_t)g * psize4];
            s0 += u & 255u; s1 += (u >> 8) & 255u;
            s2 += (u >> 16) & 255u; s3 += u >> 24;
        }
        dis[i] = rsqrtf((float)s0 + 1.0f);
        if (i + 1 < n) dis[i + 1] = rsqrtf((float)s1 + 1.0f);
        if (i + 2 < n) dis[i + 2] = rsqrtf((float)s2 + 1.0f);
        if (i + 3 < n) dis[i + 3] = rsqrtf((float)s3 + 1.0f);
    } else {
        int sb = b - ndis4;
        int i = sb * 256 + t;
        int v = M[i];
        sc[t] = v;
        __syncthreads();
        for (int d = 1; d < 256; d <<= 1) {
            int u = (t >= d) ? sc[t - d] : 0;
            __syncthreads(); sc[t] += u; __syncthreads();
        }
        M[i] = sc[t] - v;
        if (t == 255) bsum[sb] = sc[255];
    }
}

// --- coarse scatter, 1024 threads, int4 sweep (scan guarded to t<256) ---
__global__ __launch_bounds__(1024)
void k_csc(const int* __restrict__ row, const int* __restrict__ col,
           const int* __restrict__ M, const int* __restrict__ bsum,
           int* __restrict__ s4, int E, int CH, int P) {
    __shared__ int sc[256];
    __shared__ int bs[256];
    __shared__ int cur[MAXP];
    int t = threadIdx.x, b = blockIdx.x;
    if (t < 256) { int v = (t < P) ? bsum[t] : 0; sc[t] = v; bs[t] = v; }
    __syncthreads();
    for (int d = 1; d < 256; d <<= 1) {
        int u = (t < 256 && t >= d) ? sc[t - d] : 0;
        __syncthreads();
        if (t < 256) sc[t] += u;
        __syncthreads();
    }
    if (t < 256) bs[t] = sc[t] - bs[t];
    __syncthreads();
    for (int p = t; p < P; p += 1024) cur[p] = bs[p] + M[p * NB + b];
    __syncthreads();
    int s = b * CH, e = min(s + CH, E);   // multiples of 4
    for (int i = s + t * 4; i < e; i += 4096) {
        int4 r4 = *(const int4*)&row[i];
        int4 c4 = *(const int4*)&col[i];
        int p0 = atomicAdd(&cur[c4.x >> 9], 1);
        s4[p0] = (r4.x << 9) | (c4.x & 511);
        int p1 = atomicAdd(&cur[c4.y >> 9], 1);
        s4[p1] = (r4.y << 9) | (c4.y & 511);
        int p2 = atomicAdd(&cur[c4.z >> 9], 1);
        s4[p2] = (r4.z << 9) | (c4.z & 511);
        int p3 = atomicAdd(&cur[c4.w >> 9], 1);
        s4[p3] = (r4.w << 9) | (c4.w & 511);
    }
}

// --- fine counting sort, 1024 threads (scans guarded to t<256) ---
__global__ __launch_bounds__(1024)
void k_fsort(const int* __restrict__ s4, const int* __restrict__ bsum,
             int* __restrict__ rows4, int* __restrict__ off,
             int n, int E, int P) {
    __shared__ int sc[256];
    __shared__ int bs[256];
    __shared__ int hist[BW];
    __shared__ int loff[BW];
    __shared__ int tmp[256];
    int t = threadIdx.x, b = blockIdx.x;
    if (t < 256) { int v = (t < P) ? bsum[t] : 0; sc[t] = v; bs[t] = v; }
    __syncthreads();
    for (int d = 1; d < 256; d <<= 1) {
        int u = (t < 256 && t >= d) ? sc[t - d] : 0;
        __syncthreads();
        if (t < 256) sc[t] += u;
        __syncthreads();
    }
    if (t < 256) bs[t] = sc[t] - bs[t];
    __syncthreads();
    int gs = bs[b];
    int ge = gs + bsum[b];
    int c0 = b << 9;
    int lim = n - c0; if (lim > BW) lim = BW;
    for (int i = t; i < BW; i += 1024) hist[i] = 0;
    __syncthreads();
    for (int i = gs + t; i < ge; i += 1024)
        atomicAdd(&hist[s4[i] & 511], 1);
    __syncthreads();
    int s0 = 0, s1v = 0, ps = 0;
    if (t < 256) {
        s0 = hist[2 * t]; s1v = hist[2 * t + 1];
        ps = s0 + s1v;
        tmp[t] = ps;
    }
    __syncthreads();
    for (int d = 1; d < 256; d <<= 1) {
        int u = (t < 256 && t >= d) ? tmp[t - d] : 0;
        __syncthreads();
        if (t < 256) tmp[t] += u;
        __syncthreads();
    }
    if (t < 256) {
        int ex = tmp[t] - ps;
        loff[2 * t] = ex;
        loff[2 * t + 1] = ex + s0;
    }
    __syncthreads();
    for (int i = t; i < lim; i += 1024) off[c0 + i] = gs + loff[i];
    if (b == P - 1 && t == 0) off[n] = E;
    __syncthreads();
    for (int i = gs + t; i < ge; i += 1024) {
        int v2 = s4[i];
        int pos = gs + atomicAdd(&loff[v2 & 511], 1);
        rows4[pos] = v2 >> 9;
    }
}

// --- linear layer 1: g1 = bf16(dis * (concat(x,feat)@W1 + b1)) ---
__global__ __launch_bounds__(256, 4)
void k_linc(const float* __restrict__ x, const float* __restrict__ feat,
            const float* __restrict__ W, const float* __restrict__ bvec,
            const float* __restrict__ dis, bf16* __restrict__ g1, int n) {
    __shared__ float sIn[4][FDIM];
    int t = threadIdx.x;
    int local = t >> 6, j = t & 63;
    float Wreg[FDIM];
    #pragma unroll
    for (int k = 0; k < FDIM; ++k) Wreg[k] = W[k * FDIM + j];
    float bj = bvec[j];
    int gw = blockIdx.x * 4 + local;
    int nwl = GPLIN * 4;
    for (int w = gw; w < n; w += nwl) {
        sIn[local][j] = (j < 32) ? x[(size_t)w * 32 + j]
                                 : feat[(size_t)w * 32 + (j - 32)];
        __threadfence_block();
        float o = bj;
        #pragma unroll
        for (int k4 = 0; k4 < 16; ++k4) {
            float4 h4 = *(const float4*)&sIn[local][k4 * 4];
            o = fmaf(h4.x, Wreg[4 * k4 + 0], o);
            o = fmaf(h4.y, Wreg[4 * k4 + 1], o);
            o = fmaf(h4.z, Wreg[4 * k4 + 2], o);
            o = fmaf(h4.w, Wreg[4 * k4 + 3], o);
        }
        g1[(size_t)w * FDIM + j] = __float2bfloat16(dis[w] * o);
        __threadfence_block();
    }
}

// --- dual-edge gather + tail-split (proven 50.3-51.3 us): a[w][j] =
// relu(dis[w]*(g[w][j]+Σ g[r][j])). Wave = 1 node; half-wave h carries
// edge-slot parity, ushort2 per lane = 256 B (2 rows) per instruction;
// 8-deep unroll keeps 8 loads in flight. Full chunks clamp-free.
__global__ __launch_bounds__(256, 8)
void k_gather(const int* __restrict__ rows4, const int* __restrict__ off,
              const float* __restrict__ dis, const bf16* __restrict__ g,
              bf16* __restrict__ a, int n) {
    int t = blockIdx.x * blockDim.x + threadIdx.x;
    int w = t >> 6;
    if (w >= n) return;
    int lane = threadIdx.x & 63;
    int h = lane >> 5;          // edge-slot parity
    int j2 = lane & 31;         // feature pair index
    const unsigned* g32 = (const unsigned*)g;   // one row = 32 uints
    float acc0 = 0.0f, acc1 = 0.0f;
    int s = off[w], e = off[w + 1];
    int k = s;
    for (; k + 16 <= e; k += 16) {
        #pragma unroll
        for (int i = 0; i < 8; ++i) {
            int r = rows4[k + 2 * i + h];
            unsigned u = g32[(size_t)r * 32 + j2];
            acc0 += ulo2f(u);
            acc1 += uhi2f(u);
        }
    }
    if (k < e) {
        #pragma unroll
        for (int i = 0; i < 8; ++i) {
            int idx = k + 2 * i + h;
            int r = rows4[min(idx, e - 1)];
            unsigned u = g32[(size_t)r * 32 + j2];
            float wg = (idx < e) ? 1.0f : 0.0f;
            acc0 = fmaf(wg, ulo2f(u), acc0);
            acc1 = fmaf(wg, uhi2f(u), acc1);
        }
    }
    acc0 += __shfl_xor(acc0, 32, 64);
    acc1 += __shfl_xor(acc1, 32, 64);
    if (h == 0) {
        unsigned su = g32[(size_t)w * 32 + j2];    // self loop
        float dv = dis[w];
        float v0 = fmaxf(dv * (acc0 + ulo2f(su)), 0.0f);
        float v1 = fmaxf(dv * (acc1 + uhi2f(su)), 0.0f);
        ((unsigned*)a)[(size_t)w * 32 + j2] = f2bu(v0) | (f2bu(v1) << 16);
    }
}

// --- MFMA matvec: o = A@W + b ; FINAL ? relu(o) f32 : bf16(dis*o) ---
// Layouts (guide-verified): A-frag A[m=lane&15][k=quad*8+j];
// B-frag B[k=quad*8+j][n=lane&15]; C/D: n=lane&15, m=quad*4+reg.
template <bool FINAL>
__global__ __launch_bounds__(256, 4)
void k_mat(const bf16* __restrict__ A, const float* __restrict__ W,
           const float* __restrict__ bvec, const float* __restrict__ dis,
           void* __restrict__ outp, int n) {
    __shared__ __align__(16) bf16 sWt[FDIM * FDIM];   // Wt[n][k] (transposed)
    int t = threadIdx.x;
    for (int idx = t; idx < FDIM * FDIM; idx += 256) {
        int kk = idx >> 6, nn = idx & 63;
        sWt[nn * FDIM + kk] = __float2bfloat16(W[idx]);
    }
    __syncthreads();
    int wave = t >> 6, lane = t & 63;
    int quad = lane >> 4, l15 = lane & 15;
    v8s bfr[4][2];
    #pragma unroll
    for (int nt = 0; nt < 4; ++nt) {
        #pragma unroll
        for (int kf = 0; kf < 2; ++kf)
            bfr[nt][kf] = *(const v8s*)&sWt[(nt * 16 + l15) * FDIM + kf * 32 + quad * 8];
    }
    float bj[4];
    #pragma unroll
    for (int nt = 0; nt < 4; ++nt) bj[nt] = bvec[nt * 16 + l15];

    int ntiles = (n + 15) >> 4;
    int step = gridDim.x * 4;
    for (int tile = blockIdx.x * 4 + wave; tile < ntiles; tile += step) {
        int m0 = tile << 4;
        int mA = m0 + l15; if (mA >= n) mA = n - 1;
        v8s af0 = *(const v8s*)&A[(size_t)mA * FDIM + quad * 8];
        v8s af1 = *(const v8s*)&A[(size_t)mA * FDIM + 32 + quad * 8];
        v4f acc[4];
        #pragma unroll
        for (int nt = 0; nt < 4; ++nt) {
            acc[nt] = (v4f){0.f, 0.f, 0.f, 0.f};
            acc[nt] = __builtin_amdgcn_mfma_f32_16x16x32_bf16(af0, bfr[nt][0], acc[nt], 0, 0, 0);
            acc[nt] = __builtin_amdgcn_mfma_f32_16x16x32_bf16(af1, bfr[nt][1], acc[nt], 0, 0, 0);
        }
        #pragma unroll
        for (int r = 0; r < 4; ++r) {
            int node = m0 + quad * 4 + r;
            if (node >= n) continue;
            float dv = FINAL ? 0.0f : dis[node];
            #pragma unroll
            for (int nt = 0; nt < 4; ++nt) {
                int j = nt * 16 + l15;
                float o = acc[nt][r] + bj[nt];
                if (FINAL) ((float*)outp)[(size_t)node * FDIM + j] = fmaxf(o, 0.0f);
                else ((bf16*)outp)[(size_t)node * FDIM + j] = __float2bfloat16(dv * o);
            }
        }
    }
}

extern "C" void kernel_launch(void* const* d_in, const int* in_sizes, int n_in,
                              void* d_out, int out_size, void* d_ws, size_t ws_size,
                              hipStream_t stream) {
    const float* x    = (const float*)d_in[0];
    const float* feat = (const float*)d_in[1];
    const int*   ei   = (const int*)d_in[2];
    const float* W1   = (const float*)d_in[3];
    const float* b1   = (const float*)d_in[4];
    const float* W2   = (const float*)d_in[5];
    const float* b2   = (const float*)d_in[6];
    const float* Wfc  = (const float*)d_in[7];
    const float* bfc  = (const float*)d_in[8];
    float* out = (float*)d_out;

    const int n = in_sizes[0] / 32;   // 100000
    const int E = in_sizes[2] / 2;    // 1600000 (multiple of 4)
    const int* row = ei;
    const int* col = ei + E;

    const int psize = (((n + NPART - 1) / NPART) + 3) & ~3;   // 50000
    const int psize4 = psize >> 2;                            // 12500
    const int P  = (n + BW - 1) / BW;                         // 196
    const int CH = (((E + NB - 1) / NB) + 3) & ~3;            // 6252 (x4 aligned)
    const int total = P * NB;                                 // 50176
    const int ndis4 = (((n + 3) / 4) + 255) / 256;            // 98

    // ws: off[n+1] | dis[n] | M[total] | bsum[256] | s4[E] | rows4[E]
    //     | (16B-aligned) bufA(bf16 64n) | bufB(bf16 64n)
    // part (NPART*GPB*psize4 u32 = 6.4 MB) aliases bufA (consumed in k_ds1
    // before k_linc writes g1 into bufA).
    int*   off  = (int*)d_ws;
    float* dis  = (float*)(off + (size_t)n + 1);
    int*   M    = (int*)(dis + n);
    int*   bsum = M + (size_t)total;
    int*   s4    = bsum + 256;
    int*   rows4 = s4 + E;
    size_t co = (size_t)(rows4 + E - (int*)d_ws);
    co = (co + 3) & ~(size_t)3;                  // 16B align for v8s loads
    bf16*  bufA  = (bf16*)((int*)d_ws + co);
    bf16*  bufB  = bufA + (size_t)n * FDIM;
    unsigned* part = (unsigned*)bufA;

    k_h2<<<NPART * GPB + NB, 1024, 0, stream>>>(row, col, part, M, E, n,
                                                psize, psize4, P, CH);
    k_ds1<<<ndis4 + P, 256, 0, stream>>>(part, dis, M, bsum, n, psize4, ndis4, P);
    k_csc<<<NB, 1024, 0, stream>>>(row, col, M, bsum, s4, E, CH, P);
    k_fsort<<<P, 1024, 0, stream>>>(s4, bsum, rows4, off, n, E, P);
    k_linc<<<GPLIN, 256, 0, stream>>>(x, feat, W1, b1, dis, bufA, n);
    // layer 2: gather(g1)->a1 ; mat: g2 = bf16(dis*(a1@W2+b2))
    k_gather<<<(n + 3) / 4, 256, 0, stream>>>(rows4, off, dis, bufA, bufB, n);
    k_mat<false><<<512, 256, 0, stream>>>(bufB, W2, b2, dis, bufA, n);
    // fc: gather(g2)->a2 ; out = relu(a2@Wfc+bfc)
    k_gather<<<(n + 3) / 4, 256, 0, stream>>>(rows4, off, dis, bufA, bufB, n);
    k_mat<true><<<512, 256, 0, stream>>>(bufB, Wfc, bfc, dis, out, n);
}